// Round 3
// baseline (254.675 us; speedup 1.0000x reference)
//
#include <hip/hip_runtime.h>
#include <hip/hip_bf16.h>
#include <stdint.h>

typedef __bf16 bf16x8 __attribute__((ext_vector_type(8)));
typedef float  f32x4  __attribute__((ext_vector_type(4)));
typedef unsigned short u16;
typedef unsigned int   u32;
typedef u16 u16x4 __attribute__((ext_vector_type(4)));
typedef u32 u32x4 __attribute__((ext_vector_type(4)));

#define B_  32
#define N_  128
#define F_  128
#define G_  300
#define TAB_N 4096
#define TAB_SCALE 128.0f   // 1/delta ; table covers d in [0, 31.992]

__device__ __forceinline__ u16 f2b(float f){
  union { float f; u32 u; } x; x.f = f;
  u32 r = x.u + 0x7FFFu + ((x.u >> 16) & 1u);
  return (u16)(r >> 16);
}
// pack two f32 -> bf16x2 (round-half-up; 1ulp-bf16 vs RNE, negligible)
__device__ __forceinline__ u32 pack2bf(float a, float b){
  return __builtin_amdgcn_perm(__float_as_uint(b) + 0x8000u,
                               __float_as_uint(a) + 0x8000u, 0x07060302u);
}
// shifted softplus: log(0.5*exp(x)+0.5) = max(x,0) + log(0.5 + 0.5*exp(-|x|))
__device__ __forceinline__ float sspf(float x){
  return fmaxf(x, 0.0f) + __logf(0.5f + 0.5f*__expf(-fabsf(x)));
}
__device__ __forceinline__ f32x4 mfma16(bf16x8 a, bf16x8 b, f32x4 c){
  return __builtin_amdgcn_mfma_f32_16x16x32_bf16(a, b, c, 0, 0, 0);
}

// ---------------- setup: transpose+cast w_in2f to bf16 ----------------
__global__ __launch_bounds__(256) void k_setup(const float* __restrict__ w_in2f,
                                               u16* __restrict__ wi2t){
  int idx = blockIdx.x*256 + threadIdx.x;      // < 128*128
  int h = idx >> 7, ff = idx & 127;
  wi2t[idx] = f2b(w_in2f[ff*F_ + h]);          // wi2t[h][k] = w_in2f[k][h]
}

// ---------------- table generation (exact fp32, fp32 output) ----------------
// 512 blocks x (8 rows x 32 h-threads x 4 h). 8 waves/CU, 4 indep FMA chains.
__global__ __launch_bounds__(256) void k_gentab(const float* __restrict__ w_f1,
                                                const float* __restrict__ b_f1,
                                                const float* __restrict__ w_f2,
                                                const float* __restrict__ b_f2,
                                                float* __restrict__ tab){
  __shared__ float rbfs[8*G_];
  __shared__ float ssa[8*132];
  int tid = threadIdx.x;
  int t0 = blockIdx.x * 8;                     // 512 blocks x 8 table rows
  const float NG2LE = 14.4269504089f;          // gamma * log2(e) = 10*1.442695
  for (int v = tid; v < 8*G_; v += 256){
    int rr2 = v / G_;
    int k   = v - rr2*G_;
    float d = (float)(t0 + rr2) * (1.0f/TAB_SCALE);
    float c = (float)k * (30.0f/299.0f);
    float qd = d - c;
    rbfs[v] = __builtin_amdgcn_exp2f(-NG2LE * qd * qd);
  }
  __syncthreads();
  int rr = tid >> 5, h0 = (tid & 31)*4;
  float a1[4] = {0.f,0.f,0.f,0.f};
  const float* rb = rbfs + rr*G_;
  #pragma unroll 4
  for (int k = 0; k < G_; ++k){
    float s = rb[k];
    float4 w = *reinterpret_cast<const float4*>(w_f1 + k*F_ + h0);
    a1[0] = fmaf(s, w.x, a1[0]); a1[1] = fmaf(s, w.y, a1[1]);
    a1[2] = fmaf(s, w.z, a1[2]); a1[3] = fmaf(s, w.w, a1[3]);
  }
  #pragma unroll
  for (int t = 0; t < 4; ++t) ssa[rr*132 + h0 + t] = sspf(a1[t] + b_f1[h0 + t]);
  __syncthreads();
  float a2[4] = {0.f,0.f,0.f,0.f};
  const float* sr = ssa + rr*132;
  #pragma unroll 4
  for (int k = 0; k < F_; ++k){
    float s = sr[k];
    float4 w = *reinterpret_cast<const float4*>(w_f2 + k*F_ + h0);
    a2[0] = fmaf(s, w.x, a2[0]); a2[1] = fmaf(s, w.y, a2[1]);
    a2[2] = fmaf(s, w.z, a2[2]); a2[3] = fmaf(s, w.w, a2[3]);
  }
  float4 o;
  o.x = a2[0] + b_f2[h0];     o.y = a2[1] + b_f2[h0 + 1];
  o.z = a2[2] + b_f2[h0 + 2]; o.w = a2[3] + b_f2[h0 + 3];
  *reinterpret_cast<float4*>(tab + (size_t)(t0 + rr)*F_ + h0) = o;
}

// ---------------- fused interaction (+embed on first, +readout on last) ----
// grid = 512 (b x 16 i-tiles of 8 rows). LDS 76KB -> 2 blocks/CU.
__global__ __launch_bounds__(256, 2) void k_fused(
    const float* __restrict__ x_in, const u16* __restrict__ xb_in,
    const int* __restrict__ z, const float* __restrict__ emb,
    const u16* __restrict__ wi2t,  const float* __restrict__ tab,
    const float* __restrict__ r,
    const float* __restrict__ w_f2out, const float* __restrict__ b_f2out,
    const float* __restrict__ w_out,   const float* __restrict__ b_out,
    const float* __restrict__ w_aw1,   const float* __restrict__ b_aw1,
    const float* __restrict__ w_aw2,   const float* __restrict__ b_aw2,
    float* __restrict__ x_out, u16* __restrict__ xb_out, float* __restrict__ outp,
    int first, int do_out){
  __shared__ __attribute__((aligned(16))) float fsh[128][132];   // f = x@w_in2f
  __shared__ float rsh[128][3];
  __shared__ int   zsh[128];
  __shared__ __attribute__((aligned(16))) u32 scratch[2048];     // dIdx|dFrac, later ysh
  u32*   dIdx  = scratch;                       // [1024]
  float* dFrac = (float*)(scratch + 1024);      // [1024]
  float* ysh   = (float*)scratch;               // [8][132] (aliased, post-cfconv)

  int b = blockIdx.x >> 4, i0 = (blockIdx.x & 15) * 8;
  int tid = threadIdx.x, lane = tid & 63, wave = tid >> 6;
  int m = lane & 15, q = lane >> 4;

  if (tid < 128){
    const float* rp = r + (size_t)(b*N_ + tid)*3;
    rsh[tid][0] = rp[0]; rsh[tid][1] = rp[1]; rsh[tid][2] = rp[2];
    zsh[tid] = z[b*N_ + tid];
  }
  __syncthreads();

  // ---- f = x @ w_in2f via bf16 MFMA; each wave owns a 64x64 quadrant ----
  int jr = (wave >> 1)*64, kc = (wave & 1)*64;
  f32x4 acc[4][4];
  #pragma unroll
  for (int mi = 0; mi < 4; ++mi)
    #pragma unroll
    for (int ni = 0; ni < 4; ++ni) acc[mi][ni] = (f32x4){0.f,0.f,0.f,0.f};
  const u16* xbb = xb_in + (size_t)b*N_*F_;
  #pragma unroll
  for (int ks = 0; ks < 4; ++ks){
    int k0 = ks*32 + q*8;
    bf16x8 af[4], bfv[4];
    if (first){
      #pragma unroll
      for (int mi = 0; mi < 4; ++mi){
        const float* ep = emb + (size_t)zsh[jr + mi*16 + m]*F_ + k0;
        float4 e0 = *reinterpret_cast<const float4*>(ep);
        float4 e1 = *reinterpret_cast<const float4*>(ep + 4);
        u32x4 au;
        au[0] = pack2bf(e0.x, e0.y); au[1] = pack2bf(e0.z, e0.w);
        au[2] = pack2bf(e1.x, e1.y); au[3] = pack2bf(e1.z, e1.w);
        af[mi] = __builtin_bit_cast(bf16x8, au);
      }
    } else {
      #pragma unroll
      for (int mi = 0; mi < 4; ++mi)
        af[mi] = *reinterpret_cast<const bf16x8*>(xbb + (jr + mi*16 + m)*F_ + k0);
    }
    #pragma unroll
    for (int ni = 0; ni < 4; ++ni)
      bfv[ni] = *reinterpret_cast<const bf16x8*>(wi2t + (kc + ni*16 + m)*F_ + k0);
    #pragma unroll
    for (int mi = 0; mi < 4; ++mi)
      #pragma unroll
      for (int ni = 0; ni < 4; ++ni)
        acc[mi][ni] = mfma16(af[mi], bfv[ni], acc[mi][ni]);
  }

  // ---- per-pair table index/frac (overlaps MFMA latency): 1024 pairs ----
  #pragma unroll
  for (int t = 0; t < 4; ++t){
    int p = tid + t*256;                 // (il<8, j<128)
    int il = p >> 7, j = p & 127;
    int ia = i0 + il;
    float dx = rsh[ia][0] - rsh[j][0];
    float dy = rsh[ia][1] - rsh[j][1];
    float dz = rsh[ia][2] - rsh[j][2];
    float d = sqrtf(fmaf(dx,dx, fmaf(dy,dy, fmaf(dz,dz, 1e-12f))));
    float u = fminf(d * TAB_SCALE, (float)(TAB_N - 1));
    int ix = (int)u; if (ix > TAB_N - 2) ix = TAB_N - 2;
    dIdx[p]  = (u32)ix;
    dFrac[p] = u - (float)ix;
  }

  #pragma unroll
  for (int mi = 0; mi < 4; ++mi)
    #pragma unroll
    for (int ni = 0; ni < 4; ++ni)
      #pragma unroll
      for (int rr = 0; rr < 4; ++rr)
        fsh[jr + mi*16 + q*4 + rr][kc + ni*16 + m] = acc[mi][ni][rr];
  __syncthreads();

  // ---- cfconv: y[i,h] = sum_j lerp(tab, d_ij)[h] * f[j,h] ----
  int il = tid >> 5, h0 = (tid & 31)*4;
  float y0=0.f, y1=0.f, y2a=0.f, y3=0.f;
  const float* tbp = tab + h0;
  const u32* dIp = dIdx + il*128;
  const float* dFp = dFrac + il*128;
  #pragma unroll 4
  for (int j = 0; j < 128; ++j){
    u32 ix = dIp[j];
    float fr = dFp[j];
    const float* rp = tbp + ((size_t)ix << 7);
    float4 ta  = *reinterpret_cast<const float4*>(rp);
    float4 tb2 = *reinterpret_cast<const float4*>(rp + F_);
    float4 fv  = *reinterpret_cast<const float4*>(&fsh[j][h0]);
    float w0 = fmaf(fr, tb2.x - ta.x, ta.x);
    float w1 = fmaf(fr, tb2.y - ta.y, ta.y);
    float w2 = fmaf(fr, tb2.z - ta.z, ta.z);
    float w3 = fmaf(fr, tb2.w - ta.w, ta.w);
    y0 = fmaf(w0, fv.x, y0); y1 = fmaf(w1, fv.y, y1);
    y2a = fmaf(w2, fv.z, y2a); y3 = fmaf(w3, fv.w, y3);
  }
  __syncthreads();                 // all dIdx/dFrac reads done before aliasing
  ysh[il*132 + h0]     = y0; ysh[il*132 + h0 + 1] = y1;
  ysh[il*132 + h0 + 2] = y2a; ysh[il*132 + h0 + 3] = y3;
  __syncthreads();

  // ---- y2 = ssp(y @ w_f2out + b_f2out)  (fp32, exact) ----
  float a1[4] = {0.f,0.f,0.f,0.f};
  const float* yr = ysh + il*132;
  #pragma unroll 4
  for (int k = 0; k < 128; ++k){
    float yv = yr[k];
    float4 w = *reinterpret_cast<const float4*>(w_f2out + k*F_ + h0);
    a1[0] = fmaf(yv, w.x, a1[0]); a1[1] = fmaf(yv, w.y, a1[1]);
    a1[2] = fmaf(yv, w.z, a1[2]); a1[3] = fmaf(yv, w.w, a1[3]);
  }
  #pragma unroll
  for (int t = 0; t < 4; ++t) a1[t] = sspf(a1[t] + b_f2out[h0 + t]);
  __syncthreads();
  #pragma unroll
  for (int t = 0; t < 4; ++t) ysh[il*132 + h0 + t] = a1[t];
  __syncthreads();

  // ---- v = y2 @ w_out + b_out ; x_new = x_old + v ----
  float v2[4] = {0.f,0.f,0.f,0.f};
  #pragma unroll 4
  for (int k = 0; k < 128; ++k){
    float yv = yr[k];
    float4 w = *reinterpret_cast<const float4*>(w_out + k*F_ + h0);
    v2[0] = fmaf(yv, w.x, v2[0]); v2[1] = fmaf(yv, w.y, v2[1]);
    v2[2] = fmaf(yv, w.z, v2[2]); v2[3] = fmaf(yv, w.w, v2[3]);
  }
  size_t ro = ((size_t)b*N_ + i0 + il)*F_ + h0;
  float4 xi4;
  if (first) xi4 = *reinterpret_cast<const float4*>(emb + (size_t)zsh[i0 + il]*F_ + h0);
  else       xi4 = *reinterpret_cast<const float4*>(x_in + ro);
  float nv[4];
  nv[0] = xi4.x + v2[0] + b_out[h0];
  nv[1] = xi4.y + v2[1] + b_out[h0 + 1];
  nv[2] = xi4.z + v2[2] + b_out[h0 + 2];
  nv[3] = xi4.w + v2[3] + b_out[h0 + 3];

  if (!do_out){
    *reinterpret_cast<float4*>(x_out + ro) = (float4){nv[0], nv[1], nv[2], nv[3]};
    u16x4 bv; bv[0]=f2b(nv[0]); bv[1]=f2b(nv[1]); bv[2]=f2b(nv[2]); bv[3]=f2b(nv[3]);
    *reinterpret_cast<u16x4*>(xb_out + ro) = bv;
  } else {
    // ---- fused readout: out = ssp(x@w_aw1+b_aw1)@w_aw2 + b_aw2 ----
    __syncthreads();               // dense2 ysh reads done before overwrite
    #pragma unroll
    for (int t = 0; t < 4; ++t) ysh[il*132 + h0 + t] = nv[t];
    __syncthreads();
    float a3[4] = {0.f,0.f,0.f,0.f};
    #pragma unroll 4
    for (int k = 0; k < 128; ++k){
      float xv = yr[k];
      float4 w = *reinterpret_cast<const float4*>(w_aw1 + k*F_ + h0);
      a3[0] = fmaf(xv, w.x, a3[0]); a3[1] = fmaf(xv, w.y, a3[1]);
      a3[2] = fmaf(xv, w.z, a3[2]); a3[3] = fmaf(xv, w.w, a3[3]);
    }
    float s = 0.f;
    #pragma unroll
    for (int t = 0; t < 4; ++t)
      s += sspf(a3[t] + b_aw1[h0 + t]) * w_aw2[h0 + t];
    #pragma unroll
    for (int off = 16; off; off >>= 1) s += __shfl_xor(s, off, 64);
    if ((tid & 31) == 0) outp[b*N_ + i0 + il] = s + b_aw2[0];
  }
}

extern "C" void kernel_launch(void* const* d_in, const int* in_sizes, int n_in,
                              void* d_out, int out_size, void* d_ws, size_t ws_size,
                              hipStream_t stream){
  const int*   z       = (const int*)d_in[0];
  const float* r       = (const float*)d_in[1];
  const float* emb     = (const float*)d_in[2];
  const float* w_in2f  = (const float*)d_in[3];
  const float* w_f1    = (const float*)d_in[4];
  const float* b_f1    = (const float*)d_in[5];
  const float* w_f2    = (const float*)d_in[6];
  const float* b_f2    = (const float*)d_in[7];
  const float* w_f2out = (const float*)d_in[8];
  const float* b_f2out = (const float*)d_in[9];
  const float* w_out   = (const float*)d_in[10];
  const float* b_out   = (const float*)d_in[11];
  const float* w_aw1   = (const float*)d_in[12];
  const float* b_aw1   = (const float*)d_in[13];
  const float* w_aw2   = (const float*)d_in[14];
  const float* b_aw2   = (const float*)d_in[15];

  // workspace layout (8.42 MB total)
  char* ws = (char*)d_ws;
  float* x1   = (float*)(ws);                        // 2,097,152
  float* x2   = (float*)(ws + 2097152);              // 2,097,152
  u16*   xb1  = (u16*)(ws + 4194304);                // 1,048,576
  u16*   xb2  = (u16*)(ws + 5242880);                // 1,048,576
  float* tab  = (float*)(ws + 6291456);              // 2,097,152 (fp32 table)
  u16*   wi2t = (u16*)(ws + 8388608);                //    32,768

  k_setup<<<64, 256, 0, stream>>>(w_in2f, wi2t);
  k_gentab<<<512, 256, 0, stream>>>(w_f1, b_f1, w_f2, b_f2, tab);
  // L1: embed fused (reads z/emb), writes x1/xb1
  k_fused<<<512, 256, 0, stream>>>(x2, xb2, z, emb, wi2t, tab, r,
                                   w_f2out, b_f2out, w_out, b_out,
                                   w_aw1, b_aw1, w_aw2, b_aw2,
                                   x1, xb1, (float*)d_out, 1, 0);
  // L2: x1 -> x2
  k_fused<<<512, 256, 0, stream>>>(x1, xb1, z, emb, wi2t, tab, r,
                                   w_f2out, b_f2out, w_out, b_out,
                                   w_aw1, b_aw1, w_aw2, b_aw2,
                                   x2, xb2, (float*)d_out, 0, 0);
  // L3: x2 -> out (readout fused, no x store)
  k_fused<<<512, 256, 0, stream>>>(x2, xb2, z, emb, wi2t, tab, r,
                                   w_f2out, b_f2out, w_out, b_out,
                                   w_aw1, b_aw1, w_aw2, b_aw2,
                                   x1, xb1, (float*)d_out, 0, 1);
}

// Round 4
// 234.738 us; speedup vs baseline: 1.0849x; 1.0849x over previous
//
#include <hip/hip_runtime.h>
#include <hip/hip_bf16.h>
#include <stdint.h>

typedef __bf16 bf16x8 __attribute__((ext_vector_type(8)));
typedef float  f32x4  __attribute__((ext_vector_type(4)));
typedef unsigned short u16;
typedef unsigned int   u32;
typedef u16 u16x4 __attribute__((ext_vector_type(4)));
typedef u32 u32x4 __attribute__((ext_vector_type(4)));

#define B_  32
#define N_  128
#define F_  128
#define G_  300
#define TAB_N 4096
#define TAB_SCALE 128.0f   // 1/delta ; table covers d in [0, 31.992]

__device__ __forceinline__ u16 f2b(float f){
  union { float f; u32 u; } x; x.f = f;
  u32 r = x.u + 0x7FFFu + ((x.u >> 16) & 1u);
  return (u16)(r >> 16);
}
// pack two f32 -> bf16x2 (round-half-up)
__device__ __forceinline__ u32 pack2bf(float a, float b){
  return __builtin_amdgcn_perm(__float_as_uint(b) + 0x8000u,
                               __float_as_uint(a) + 0x8000u, 0x07060302u);
}
// shifted softplus
__device__ __forceinline__ float sspf(float x){
  return fmaxf(x, 0.0f) + __logf(0.5f + 0.5f*__expf(-fabsf(x)));
}
__device__ __forceinline__ f32x4 mfma16(bf16x8 a, bf16x8 b, f32x4 c){
  return __builtin_amdgcn_mfma_f32_16x16x32_bf16(a, b, c, 0, 0, 0);
}

// ---------------- setup: transpose+cast w_in2f to bf16 ----------------
__global__ __launch_bounds__(256) void k_setup(const float* __restrict__ w_in2f,
                                               u16* __restrict__ wi2t){
  int idx = blockIdx.x*256 + threadIdx.x;      // < 128*128
  int h = idx >> 7, ff = idx & 127;
  wi2t[idx] = f2b(w_in2f[ff*F_ + h]);          // wi2t[h][k] = w_in2f[k][h]
}

// ---------------- table generation (exact fp32 math, bf16 output) ----------
// 512 blocks x (8 rows x 32 h-threads x 4 h).
__global__ __launch_bounds__(256) void k_gentab(const float* __restrict__ w_f1,
                                                const float* __restrict__ b_f1,
                                                const float* __restrict__ w_f2,
                                                const float* __restrict__ b_f2,
                                                u16* __restrict__ tab){
  __shared__ float rbfs[8*G_];
  __shared__ float ssa[8*132];
  int tid = threadIdx.x;
  int t0 = blockIdx.x * 8;
  const float NG2LE = 14.4269504089f;          // gamma * log2(e)
  for (int v = tid; v < 8*G_; v += 256){
    int rr2 = v / G_;
    int k   = v - rr2*G_;
    float d = (float)(t0 + rr2) * (1.0f/TAB_SCALE);
    float c = (float)k * (30.0f/299.0f);
    float qd = d - c;
    rbfs[v] = __builtin_amdgcn_exp2f(-NG2LE * qd * qd);
  }
  __syncthreads();
  int rr = tid >> 5, h0 = (tid & 31)*4;
  float a1[4] = {0.f,0.f,0.f,0.f};
  const float* rb = rbfs + rr*G_;
  #pragma unroll 4
  for (int k = 0; k < G_; ++k){
    float s = rb[k];
    float4 w = *reinterpret_cast<const float4*>(w_f1 + k*F_ + h0);
    a1[0] = fmaf(s, w.x, a1[0]); a1[1] = fmaf(s, w.y, a1[1]);
    a1[2] = fmaf(s, w.z, a1[2]); a1[3] = fmaf(s, w.w, a1[3]);
  }
  #pragma unroll
  for (int t = 0; t < 4; ++t) ssa[rr*132 + h0 + t] = sspf(a1[t] + b_f1[h0 + t]);
  __syncthreads();
  float a2[4] = {0.f,0.f,0.f,0.f};
  const float* sr = ssa + rr*132;
  #pragma unroll 4
  for (int k = 0; k < F_; ++k){
    float s = sr[k];
    float4 w = *reinterpret_cast<const float4*>(w_f2 + k*F_ + h0);
    a2[0] = fmaf(s, w.x, a2[0]); a2[1] = fmaf(s, w.y, a2[1]);
    a2[2] = fmaf(s, w.z, a2[2]); a2[3] = fmaf(s, w.w, a2[3]);
  }
  u16x4 ov;
  ov[0] = f2b(a2[0] + b_f2[h0]);     ov[1] = f2b(a2[1] + b_f2[h0 + 1]);
  ov[2] = f2b(a2[2] + b_f2[h0 + 2]); ov[3] = f2b(a2[3] + b_f2[h0 + 3]);
  *reinterpret_cast<u16x4*>(tab + (size_t)(t0 + rr)*F_ + h0) = ov;
}

// ---------------- f = x @ w_in2f -> bf16 global (MFMA) ----------------
// grid 128: (b, 32-row quarter). No LDS; frags straight from global.
__global__ __launch_bounds__(256) void k_lin(const u16* __restrict__ xb,
                                             const int* __restrict__ z,
                                             const float* __restrict__ emb,
                                             const u16* __restrict__ wi2t,
                                             u16* __restrict__ fb, int first){
  int bi = blockIdx.x;
  int b = bi >> 2, qd = bi & 3;
  int tid = threadIdx.x, lane = tid & 63, wave = tid >> 6;
  int m = lane & 15, q = lane >> 4;
  int R0 = qd*32 + (wave >> 1)*16;       // 16 rows per wave
  int C0 = (wave & 1)*64;                // 64 cols per wave
  int row = R0 + m;
  const u16*   xrow = xb + ((size_t)b*N_ + row)*F_;
  const float* erow = emb;
  if (first) erow = emb + (size_t)z[b*N_ + row]*F_;
  f32x4 acc[4];
  #pragma unroll
  for (int ni = 0; ni < 4; ++ni) acc[ni] = (f32x4){0.f,0.f,0.f,0.f};
  #pragma unroll
  for (int ks = 0; ks < 4; ++ks){
    int k0 = ks*32 + q*8;
    bf16x8 af;
    if (first){
      float4 e0 = *reinterpret_cast<const float4*>(erow + k0);
      float4 e1 = *reinterpret_cast<const float4*>(erow + k0 + 4);
      u32x4 au;
      au[0] = pack2bf(e0.x, e0.y); au[1] = pack2bf(e0.z, e0.w);
      au[2] = pack2bf(e1.x, e1.y); au[3] = pack2bf(e1.z, e1.w);
      af = __builtin_bit_cast(bf16x8, au);
    } else {
      af = *reinterpret_cast<const bf16x8*>(xrow + k0);
    }
    bf16x8 bfv[4];
    #pragma unroll
    for (int ni = 0; ni < 4; ++ni)
      bfv[ni] = *reinterpret_cast<const bf16x8*>(wi2t + (C0 + ni*16 + m)*F_ + k0);
    #pragma unroll
    for (int ni = 0; ni < 4; ++ni)
      acc[ni] = mfma16(af, bfv[ni], acc[ni]);
  }
  u16* fbb = fb + (size_t)b*N_*F_;
  #pragma unroll
  for (int ni = 0; ni < 4; ++ni)
    #pragma unroll
    for (int rr = 0; rr < 4; ++rr)
      fbb[(size_t)(R0 + q*4 + rr)*F_ + C0 + ni*16 + m] = f2b(acc[ni][rr]);
}

// ---------------- fused cfconv + MLP + residual (+readout on last) --------
// grid = 512 (b x 16 tiles of 8 rows), 512 threads, LDS 28.8 KB -> 2 blk/CU.
__global__ __launch_bounds__(512, 4) void k_fused(
    const float* __restrict__ x_in, const u16* __restrict__ fb,
    const u16* __restrict__ tab,
    const int* __restrict__ z, const float* __restrict__ emb,
    const float* __restrict__ r,
    const float* __restrict__ w_f2out, const float* __restrict__ b_f2out,
    const float* __restrict__ w_out,   const float* __restrict__ b_out,
    const float* __restrict__ w_aw1,   const float* __restrict__ b_aw1,
    const float* __restrict__ w_aw2,   const float* __restrict__ b_aw2,
    float* __restrict__ x_out, u16* __restrict__ xb_out, float* __restrict__ outp,
    int first, int do_out){
  __shared__ __attribute__((aligned(16))) float psh[4][8*132];  // partials (cfconv/dense)
  __shared__ __attribute__((aligned(16))) float ysh[8*132];
  __shared__ float rsh[128][3];
  __shared__ u16   dIdxS[1024];
  __shared__ float dFracS[1024];

  int bid = blockIdx.x;
  int b = bid >> 4, i0 = (bid & 15)*8;
  int tid = threadIdx.x;

  if (tid < 128){
    const float* rp = r + (size_t)(b*N_ + tid)*3;
    rsh[tid][0] = rp[0]; rsh[tid][1] = rp[1]; rsh[tid][2] = rp[2];
  }
  __syncthreads();

  // ---- pair phase: 1024 pairs (8 il x 128 j), 2 per thread ----
  #pragma unroll
  for (int t = 0; t < 2; ++t){
    int p = tid + t*512;
    int il = p >> 7, j = p & 127;
    int ia = i0 + il;
    float dx = rsh[ia][0] - rsh[j][0];
    float dy = rsh[ia][1] - rsh[j][1];
    float dz = rsh[ia][2] - rsh[j][2];
    float d = sqrtf(fmaf(dx,dx, fmaf(dy,dy, fmaf(dz,dz, 1e-12f))));
    float u = fminf(d * TAB_SCALE, (float)(TAB_N - 1));
    int ix = (int)u; if (ix > TAB_N - 2) ix = TAB_N - 2;
    dIdxS[p]  = (u16)ix;
    dFracS[p] = u - (float)ix;
  }
  __syncthreads();

  // ---- cfconv: thread = (j-quarter jq<4, il<8, ch-group chg<16 of 8 ch) ----
  int jq  = tid >> 7;
  int il  = (tid >> 4) & 7;
  int chg = tid & 15;
  int h0  = chg*8;
  float y[8] = {0,0,0,0,0,0,0,0};
  const u16* tb0 = tab + h0;
  const u16* fbp = fb + (size_t)b*N_*F_ + h0;
  int jbase = jq*32;
  #pragma unroll 4
  for (int jj = 0; jj < 32; ++jj){
    int j = jbase + jj;
    int p = il*128 + j;
    u32 ix  = dIdxS[p];
    float fr = dFracS[p];
    const u16* rp = tb0 + ((size_t)ix << 7);
    bf16x8 ta  = *reinterpret_cast<const bf16x8*>(rp);
    bf16x8 tb2 = *reinterpret_cast<const bf16x8*>(rp + F_);
    bf16x8 fv  = *reinterpret_cast<const bf16x8*>(fbp + (size_t)j*F_);
    #pragma unroll
    for (int t = 0; t < 8; ++t){
      float a = (float)ta[t];
      float w = fmaf(fr, (float)tb2[t] - a, a);
      y[t] = fmaf(w, (float)fv[t], y[t]);
    }
  }
  {
    float* pp = &psh[jq][il*132 + h0];
    *reinterpret_cast<float4*>(pp)     = (float4){y[0], y[1], y[2], y[3]};
    *reinterpret_cast<float4*>(pp + 4) = (float4){y[4], y[5], y[6], y[7]};
  }
  __syncthreads();
  // reduce 4 j-quarters -> ysh (1024 outputs, 2/thread)
  #pragma unroll
  for (int t = 0; t < 2; ++t){
    int o = tid + t*512;
    int oil = o >> 7, ch = o & 127;
    int ofs = oil*132 + ch;
    ysh[ofs] = psh[0][ofs] + psh[1][ofs] + psh[2][ofs] + psh[3][ofs];
  }
  __syncthreads();

  // ---- dense1: y2 = ssp(y @ w_f2out + b)  (k-split x2) ----
  int kh  = tid >> 8;             // 0..1
  int dil = (tid >> 5) & 7;
  int c4  = (tid & 31)*4;
  const float* yr = ysh + dil*132;
  {
    float a1[4] = {0.f,0.f,0.f,0.f};
    int kb = kh*64;
    #pragma unroll 4
    for (int kk = 0; kk < 64; ++kk){
      int k = kb + kk;
      float yv = yr[k];
      float4 w = *reinterpret_cast<const float4*>(w_f2out + k*F_ + c4);
      a1[0] = fmaf(yv, w.x, a1[0]); a1[1] = fmaf(yv, w.y, a1[1]);
      a1[2] = fmaf(yv, w.z, a1[2]); a1[3] = fmaf(yv, w.w, a1[3]);
    }
    *reinterpret_cast<float4*>(&psh[kh][dil*132 + c4]) = (float4){a1[0],a1[1],a1[2],a1[3]};
  }
  __syncthreads();
  #pragma unroll
  for (int t = 0; t < 2; ++t){
    int o = tid + t*512;
    int oil = o >> 7, ch = o & 127;
    int ofs = oil*132 + ch;
    ysh[ofs] = sspf(psh[0][ofs] + psh[1][ofs] + b_f2out[ch]);
  }
  __syncthreads();

  // ---- dense2: v = y2 @ w_out  (k-split x2) ----
  {
    float a2[4] = {0.f,0.f,0.f,0.f};
    int kb = kh*64;
    #pragma unroll 4
    for (int kk = 0; kk < 64; ++kk){
      int k = kb + kk;
      float yv = yr[k];
      float4 w = *reinterpret_cast<const float4*>(w_out + k*F_ + c4);
      a2[0] = fmaf(yv, w.x, a2[0]); a2[1] = fmaf(yv, w.y, a2[1]);
      a2[2] = fmaf(yv, w.z, a2[2]); a2[3] = fmaf(yv, w.w, a2[3]);
    }
    *reinterpret_cast<float4*>(&psh[kh][dil*132 + c4]) = (float4){a2[0],a2[1],a2[2],a2[3]};
  }
  __syncthreads();

  // ---- epilogue: x_new = x_old + v + b_out ----
  if (tid < 256){
    int eil = tid >> 5, ec = (tid & 31)*4;
    int ofs = eil*132 + ec;
    float4 p0 = *reinterpret_cast<float4*>(&psh[0][ofs]);
    float4 p1 = *reinterpret_cast<float4*>(&psh[1][ofs]);
    float4 bo = *reinterpret_cast<const float4*>(b_out + ec);
    size_t ro = ((size_t)b*N_ + i0 + eil)*F_ + ec;
    float4 xi;
    if (first) xi = *reinterpret_cast<const float4*>(emb + (size_t)z[b*N_ + i0 + eil]*F_ + ec);
    else       xi = *reinterpret_cast<const float4*>(x_in + ro);
    float nv0 = xi.x + p0.x + p1.x + bo.x;
    float nv1 = xi.y + p0.y + p1.y + bo.y;
    float nv2 = xi.z + p0.z + p1.z + bo.z;
    float nv3 = xi.w + p0.w + p1.w + bo.w;
    if (!do_out){
      *reinterpret_cast<float4*>(x_out + ro) = (float4){nv0, nv1, nv2, nv3};
      u16x4 bv; bv[0]=f2b(nv0); bv[1]=f2b(nv1); bv[2]=f2b(nv2); bv[3]=f2b(nv3);
      *reinterpret_cast<u16x4*>(xb_out + ro) = bv;
    } else {
      ysh[ofs] = nv0; ysh[ofs+1] = nv1; ysh[ofs+2] = nv2; ysh[ofs+3] = nv3;
    }
  }

  if (do_out){
    __syncthreads();
    if (tid < 256){
      int eil = tid >> 5, hg = (tid & 31)*4;
      const float* xr = ysh + eil*132;
      float a3[4] = {0.f,0.f,0.f,0.f};
      #pragma unroll 4
      for (int k = 0; k < 128; ++k){
        float xv = xr[k];
        float4 w = *reinterpret_cast<const float4*>(w_aw1 + k*F_ + hg);
        a3[0] = fmaf(xv, w.x, a3[0]); a3[1] = fmaf(xv, w.y, a3[1]);
        a3[2] = fmaf(xv, w.z, a3[2]); a3[3] = fmaf(xv, w.w, a3[3]);
      }
      float s = 0.f;
      #pragma unroll
      for (int t = 0; t < 4; ++t)
        s += sspf(a3[t] + b_aw1[hg + t]) * w_aw2[hg + t];
      #pragma unroll
      for (int off = 16; off; off >>= 1) s += __shfl_xor(s, off, 64);
      if ((tid & 31) == 0) outp[b*N_ + i0 + eil] = s + b_aw2[0];
    }
  }
}

extern "C" void kernel_launch(void* const* d_in, const int* in_sizes, int n_in,
                              void* d_out, int out_size, void* d_ws, size_t ws_size,
                              hipStream_t stream){
  const int*   z       = (const int*)d_in[0];
  const float* r       = (const float*)d_in[1];
  const float* emb     = (const float*)d_in[2];
  const float* w_in2f  = (const float*)d_in[3];
  const float* w_f1    = (const float*)d_in[4];
  const float* b_f1    = (const float*)d_in[5];
  const float* w_f2    = (const float*)d_in[6];
  const float* b_f2    = (const float*)d_in[7];
  const float* w_f2out = (const float*)d_in[8];
  const float* b_f2out = (const float*)d_in[9];
  const float* w_out   = (const float*)d_in[10];
  const float* b_out   = (const float*)d_in[11];
  const float* w_aw1   = (const float*)d_in[12];
  const float* b_aw1   = (const float*)d_in[13];
  const float* w_aw2   = (const float*)d_in[14];
  const float* b_aw2   = (const float*)d_in[15];

  // workspace layout (7.2 MB)
  char* ws = (char*)d_ws;
  float* x1   = (float*)(ws);                        // 2,097,152
  float* x2   = (float*)(ws + 2097152);              // 2,097,152
  u16*   xb   = (u16*)(ws + 4194304);                // 1,048,576
  u16*   fbuf = (u16*)(ws + 5242880);                // 1,048,576
  u16*   tab  = (u16*)(ws + 6291456);                // 1,048,576 (bf16 table)
  u16*   wi2t = (u16*)(ws + 7340032);                //    32,768

  k_setup<<<64, 256, 0, stream>>>(w_in2f, wi2t);
  k_gentab<<<512, 256, 0, stream>>>(w_f1, b_f1, w_f2, b_f2, tab);
  // iter 1 (embed fused into k_lin + residual-from-emb in k_fused)
  k_lin<<<128, 256, 0, stream>>>(xb, z, emb, wi2t, fbuf, 1);
  k_fused<<<512, 512, 0, stream>>>(x2, fbuf, tab, z, emb, r,
                                   w_f2out, b_f2out, w_out, b_out,
                                   w_aw1, b_aw1, w_aw2, b_aw2,
                                   x1, xb, (float*)d_out, 1, 0);
  // iter 2
  k_lin<<<128, 256, 0, stream>>>(xb, z, emb, wi2t, fbuf, 0);
  k_fused<<<512, 512, 0, stream>>>(x1, fbuf, tab, z, emb, r,
                                   w_f2out, b_f2out, w_out, b_out,
                                   w_aw1, b_aw1, w_aw2, b_aw2,
                                   x2, xb, (float*)d_out, 0, 0);
  // iter 3 (readout fused)
  k_lin<<<128, 256, 0, stream>>>(xb, z, emb, wi2t, fbuf, 0);
  k_fused<<<512, 512, 0, stream>>>(x2, fbuf, tab, z, emb, r,
                                   w_f2out, b_f2out, w_out, b_out,
                                   w_aw1, b_aw1, w_aw2, b_aw2,
                                   x1, xb, (float*)d_out, 0, 1);
}

// Round 5
// 167.860 us; speedup vs baseline: 1.5172x; 1.3984x over previous
//
#include <hip/hip_runtime.h>
#include <hip/hip_bf16.h>
#include <stdint.h>

typedef __bf16 bf16x8 __attribute__((ext_vector_type(8)));
typedef float  f32x4  __attribute__((ext_vector_type(4)));
typedef unsigned short u16;
typedef unsigned int   u32;
typedef u16 u16x4 __attribute__((ext_vector_type(4)));
typedef u32 u32x4 __attribute__((ext_vector_type(4)));

#define B_  32
#define N_  128
#define F_  128
#define G_  300
#define GP  320
#define TAB_N 4096
#define TAB_SCALE 128.0f   // 1/delta ; table covers d in [0, 31.992]

__device__ __forceinline__ u16 f2b(float f){
  union { float f; u32 u; } x; x.f = f;
  u32 r = x.u + 0x7FFFu + ((x.u >> 16) & 1u);
  return (u16)(r >> 16);
}
// pack two f32 -> bf16x2 (low = a, high = b)
__device__ __forceinline__ u32 pack2bf(float a, float b){
  return __builtin_amdgcn_perm(__float_as_uint(b) + 0x8000u,
                               __float_as_uint(a) + 0x8000u, 0x07060302u);
}
// shifted softplus
__device__ __forceinline__ float sspf(float x){
  return fmaxf(x, 0.0f) + __logf(0.5f + 0.5f*__expf(-fabsf(x)));
}
__device__ __forceinline__ f32x4 mfma16(bf16x8 a, bf16x8 b, f32x4 c){
  return __builtin_amdgcn_mfma_f32_16x16x32_bf16(a, b, c, 0, 0, 0);
}

// ---------------- setup: transpose+cast all weights to bf16 [h][k] ---------
// w1t[128][320] (zero-pad K 300->320), then 5x 128x128: w2t, wi2t, w2outT, woutT, waw1T
__global__ __launch_bounds__(256) void k_setup(const float* __restrict__ w_f1,
                                               const float* __restrict__ w_f2,
                                               const float* __restrict__ w_in2f,
                                               const float* __restrict__ w_f2out,
                                               const float* __restrict__ w_out,
                                               const float* __restrict__ w_aw1,
                                               u16* __restrict__ w1t,
                                               u16* __restrict__ w2t,
                                               u16* __restrict__ wi2t,
                                               u16* __restrict__ w2outT,
                                               u16* __restrict__ woutT,
                                               u16* __restrict__ waw1T){
  int idx = blockIdx.x*256 + threadIdx.x;      // < 40960 + 5*16384 = 122880
  if (idx < 128*GP){
    int h = idx / GP, g = idx % GP;
    w1t[idx] = (g < G_) ? f2b(w_f1[g*F_ + h]) : (u16)0;
  } else {
    int j = idx - 128*GP;
    int which = j >> 14;
    int rr = j & 16383;
    int h = rr >> 7, k = rr & 127;
    const float* src; u16* dst;
    switch (which){
      case 0:  src = w_f2;    dst = w2t;    break;
      case 1:  src = w_in2f;  dst = wi2t;   break;
      case 2:  src = w_f2out; dst = w2outT; break;
      case 3:  src = w_out;   dst = woutT;  break;
      default: src = w_aw1;   dst = waw1T;  break;
    }
    dst[h*128 + k] = f2b(src[k*128 + h]);
  }
}

// ---------------- table generation via MFMA ----------------
// grid 256: 16 table rows per block; rbf A-frags in-register (exp2), K1=320, K2=128.
__global__ __launch_bounds__(256) void k_gentab(const u16* __restrict__ w1t,
                                                const u16* __restrict__ w2t,
                                                const float* __restrict__ b_f1,
                                                const float* __restrict__ b_f2,
                                                u16* __restrict__ tab){
  __shared__ __attribute__((aligned(16))) u16 w1s[16][136];
  int tid = threadIdx.x, lane = tid & 63, wave = tid >> 6;
  int m = lane & 15, q = lane >> 4;
  int t0 = blockIdx.x * 16;
  int C0 = wave*32;
  const float K2 = 14.4269504089f;             // gamma * log2(e)
  const float DC = 30.0f/299.0f;               // center spacing
  float d = (float)(t0 + m) * (1.0f/TAB_SCALE);

  f32x4 acc[2];
  acc[0] = (f32x4){0.f,0.f,0.f,0.f}; acc[1] = (f32x4){0.f,0.f,0.f,0.f};
  #pragma unroll
  for (int ks = 0; ks < 10; ++ks){
    int kb = ks*32 + q*8;
    u32x4 au;
    #pragma unroll
    for (int t2 = 0; t2 < 4; ++t2){
      int k0 = kb + t2*2;
      float u0 = d - DC*(float)k0;
      float u1 = d - DC*(float)(k0 + 1);
      float e0 = __builtin_amdgcn_exp2f(-K2*u0*u0);
      float e1 = __builtin_amdgcn_exp2f(-K2*u1*u1);
      au[t2] = pack2bf(e0, e1);
    }
    bf16x8 af = __builtin_bit_cast(bf16x8, au);
    #pragma unroll
    for (int ni = 0; ni < 2; ++ni){
      bf16x8 bfv = *reinterpret_cast<const bf16x8*>(w1t + (size_t)(C0 + ni*16 + m)*GP + kb);
      acc[ni] = mfma16(af, bfv, acc[ni]);
    }
  }
  #pragma unroll
  for (int ni = 0; ni < 2; ++ni)
    #pragma unroll
    for (int rr = 0; rr < 4; ++rr){
      int col = C0 + ni*16 + m;
      w1s[q*4 + rr][col & 127] = f2b(sspf(acc[ni][rr] + b_f1[col]));
    }
  __syncthreads();

  f32x4 acc2[2];
  acc2[0] = (f32x4){0.f,0.f,0.f,0.f}; acc2[1] = (f32x4){0.f,0.f,0.f,0.f};
  #pragma unroll
  for (int ks = 0; ks < 4; ++ks){
    int kb = ks*32 + q*8;
    bf16x8 af = *reinterpret_cast<const bf16x8*>(&w1s[m][kb]);
    #pragma unroll
    for (int ni = 0; ni < 2; ++ni){
      bf16x8 bfv = *reinterpret_cast<const bf16x8*>(w2t + (size_t)(C0 + ni*16 + m)*128 + kb);
      acc2[ni] = mfma16(af, bfv, acc2[ni]);
    }
  }
  #pragma unroll
  for (int ni = 0; ni < 2; ++ni)
    #pragma unroll
    for (int rr = 0; rr < 4; ++rr){
      int col = C0 + ni*16 + m;
      tab[(size_t)(t0 + q*4 + rr)*F_ + col] = f2b(acc2[ni][rr] + b_f2[col]);
    }
}

// ---------------- f = emb[z] @ w_in2f -> bf16 global (MFMA, iter 1 only) ----
__global__ __launch_bounds__(256) void k_lin(const int* __restrict__ z,
                                             const float* __restrict__ emb,
                                             const u16* __restrict__ wi2t,
                                             u16* __restrict__ fb){
  int bi = blockIdx.x;
  int b = bi >> 2, qd = bi & 3;
  int tid = threadIdx.x, lane = tid & 63, wave = tid >> 6;
  int m = lane & 15, q = lane >> 4;
  int R0 = qd*32 + (wave >> 1)*16;
  int C0 = (wave & 1)*64;
  int row = R0 + m;
  const float* erow = emb + (size_t)z[b*N_ + row]*F_;
  f32x4 acc[4];
  #pragma unroll
  for (int ni = 0; ni < 4; ++ni) acc[ni] = (f32x4){0.f,0.f,0.f,0.f};
  #pragma unroll
  for (int ks = 0; ks < 4; ++ks){
    int k0 = ks*32 + q*8;
    float4 e0 = *reinterpret_cast<const float4*>(erow + k0);
    float4 e1 = *reinterpret_cast<const float4*>(erow + k0 + 4);
    u32x4 au;
    au[0] = pack2bf(e0.x, e0.y); au[1] = pack2bf(e0.z, e0.w);
    au[2] = pack2bf(e1.x, e1.y); au[3] = pack2bf(e1.z, e1.w);
    bf16x8 af = __builtin_bit_cast(bf16x8, au);
    #pragma unroll
    for (int ni = 0; ni < 4; ++ni){
      bf16x8 bfv = *reinterpret_cast<const bf16x8*>(wi2t + (size_t)(C0 + ni*16 + m)*F_ + k0);
      acc[ni] = mfma16(af, bfv, acc[ni]);
    }
  }
  u16* fbb = fb + (size_t)b*N_*F_;
  #pragma unroll
  for (int ni = 0; ni < 4; ++ni)
    #pragma unroll
    for (int rr = 0; rr < 4; ++rr)
      fbb[(size_t)(R0 + q*4 + rr)*F_ + C0 + ni*16 + m] = f2b(acc[ni][rr]);
}

// ---------------- cfconv only: y[i,h] = sum_j lerp(tab,d_ij)[h] * f[j,h] ----
// grid = 1024 (b x 32 tiles of 4 rows), 256 thr = (jq4, il4, chg16). LDS 13 KB.
__global__ __launch_bounds__(256, 4) void k_conv(const u16* __restrict__ fb,
                                                 const u16* __restrict__ tab,
                                                 const float* __restrict__ r,
                                                 float* __restrict__ y){
  __shared__ float rsh[128][3];
  __shared__ u16   dIdxS[512];
  __shared__ float dFracS[512];
  __shared__ __attribute__((aligned(16))) float psh[4][4*132];

  int bid = blockIdx.x;
  int b = bid >> 5, i0 = (bid & 31)*4;
  int tid = threadIdx.x;

  if (tid < 128){
    const float* rp = r + (size_t)(b*N_ + tid)*3;
    rsh[tid][0] = rp[0]; rsh[tid][1] = rp[1]; rsh[tid][2] = rp[2];
  }
  __syncthreads();

  #pragma unroll
  for (int t = 0; t < 2; ++t){
    int p = tid + t*256;                 // 512 pairs: (il<4, j<128)
    int il = p >> 7, j = p & 127;
    int ia = i0 + il;
    float dx = rsh[ia][0] - rsh[j][0];
    float dy = rsh[ia][1] - rsh[j][1];
    float dz = rsh[ia][2] - rsh[j][2];
    float d = sqrtf(fmaf(dx,dx, fmaf(dy,dy, fmaf(dz,dz, 1e-12f))));
    float u = fminf(d * TAB_SCALE, (float)(TAB_N - 1));
    int ix = (int)u; if (ix > TAB_N - 2) ix = TAB_N - 2;
    dIdxS[p]  = (u16)ix;
    dFracS[p] = u - (float)ix;
  }
  __syncthreads();

  int chg = tid & 15, il = (tid >> 4) & 3, jq = tid >> 6;
  int h0 = chg*8;
  float yv[8] = {0,0,0,0,0,0,0,0};
  const u16* tb0 = tab + h0;
  const u16* fbp = fb + (size_t)b*N_*F_ + h0;
  int pbase = il*128 + jq*32;
  #pragma unroll 4
  for (int jj = 0; jj < 32; ++jj){
    int p = pbase + jj;
    u32 ix  = dIdxS[p];
    float fr = dFracS[p];
    const u16* rp = tb0 + ((size_t)ix << 7);
    bf16x8 ta  = *reinterpret_cast<const bf16x8*>(rp);
    bf16x8 tb2 = *reinterpret_cast<const bf16x8*>(rp + F_);
    bf16x8 fv  = *reinterpret_cast<const bf16x8*>(fbp + (size_t)(jq*32 + jj)*F_);
    #pragma unroll
    for (int t = 0; t < 8; ++t){
      float a = (float)ta[t];
      float w = fmaf(fr, (float)tb2[t] - a, a);
      yv[t] = fmaf(w, (float)fv[t], yv[t]);
    }
  }
  {
    float* pp = &psh[jq][il*132 + h0];
    *reinterpret_cast<float4*>(pp)     = (float4){yv[0], yv[1], yv[2], yv[3]};
    *reinterpret_cast<float4*>(pp + 4) = (float4){yv[4], yv[5], yv[6], yv[7]};
  }
  __syncthreads();
  #pragma unroll
  for (int t = 0; t < 2; ++t){
    int o = tid + t*256;                 // 512 outputs (oil<4, ch<128)
    int oil = o >> 7, ch = o & 127;
    int ofs = oil*132 + ch;
    y[((size_t)(b*N_ + i0 + oil))*F_ + ch] =
      psh[0][ofs] + psh[1][ofs] + psh[2][ofs] + psh[3][ofs];
  }
}

// ---------------- MLP chain via MFMA: dense1+ssp+dense2+residual, then ------
// mode 0: f_next = x_new @ w_in2f -> fb ; mode 1: fused readout -> outp.
// grid 256: (b, 16-row tile). In-place x (block touches only its own rows).
__global__ __launch_bounds__(256) void k_mlp(const float* __restrict__ y,
                                             float* __restrict__ x,
                                             const int* __restrict__ z,
                                             const float* __restrict__ emb,
                                             const u16* __restrict__ w2outT,
                                             const float* __restrict__ b_f2out,
                                             const u16* __restrict__ woutT,
                                             const float* __restrict__ b_out,
                                             const u16* __restrict__ wi2t,
                                             const u16* __restrict__ waw1T,
                                             const float* __restrict__ b_aw1,
                                             const float* __restrict__ w_aw2,
                                             const float* __restrict__ b_aw2,
                                             u16* __restrict__ fb,
                                             float* __restrict__ outp,
                                             int first, int mode){
  __shared__ __attribute__((aligned(16))) u16 ab[16][136];
  __shared__ float cs[16][132];
  __shared__ float psum[16][8];
  __shared__ int zsh[16];
  int tid = threadIdx.x, lane = tid & 63, wave = tid >> 6;
  int m = lane & 15, q = lane >> 4;
  int bid = blockIdx.x;
  int b = bid >> 3, R0 = (bid & 7)*16;
  int C0 = wave*32;

  if (first && tid < 16) zsh[tid] = z[b*N_ + R0 + tid];
  { // stage y -> bf16 A operand
    int row = tid >> 4, c8 = (tid & 15)*8;
    const float* yp = y + ((size_t)(b*N_ + R0 + row))*F_ + c8;
    float4 a = *reinterpret_cast<const float4*>(yp);
    float4 bq = *reinterpret_cast<const float4*>(yp + 4);
    u32x4 au;
    au[0] = pack2bf(a.x, a.y);  au[1] = pack2bf(a.z, a.w);
    au[2] = pack2bf(bq.x, bq.y); au[3] = pack2bf(bq.z, bq.w);
    *reinterpret_cast<u32x4*>(&ab[row][c8]) = au;
  }
  __syncthreads();

  // GEMM1: y @ w_f2out
  f32x4 acc[2];
  acc[0] = (f32x4){0.f,0.f,0.f,0.f}; acc[1] = (f32x4){0.f,0.f,0.f,0.f};
  #pragma unroll
  for (int ks = 0; ks < 4; ++ks){
    int kb = ks*32 + q*8;
    bf16x8 af = *reinterpret_cast<const bf16x8*>(&ab[m][kb]);
    #pragma unroll
    for (int ni = 0; ni < 2; ++ni){
      bf16x8 bfv = *reinterpret_cast<const bf16x8*>(w2outT + (size_t)(C0 + ni*16 + m)*F_ + kb);
      acc[ni] = mfma16(af, bfv, acc[ni]);
    }
  }
  __syncthreads();     // all ab reads done
  #pragma unroll
  for (int ni = 0; ni < 2; ++ni)
    #pragma unroll
    for (int rr = 0; rr < 4; ++rr){
      int col = C0 + ni*16 + m;
      ab[q*4 + rr][col & 127] = f2b(sspf(acc[ni][rr] + b_f2out[col]));
    }
  __syncthreads();

  // GEMM2: y2 @ w_out
  f32x4 acc2[2];
  acc2[0] = (f32x4){0.f,0.f,0.f,0.f}; acc2[1] = (f32x4){0.f,0.f,0.f,0.f};
  #pragma unroll
  for (int ks = 0; ks < 4; ++ks){
    int kb = ks*32 + q*8;
    bf16x8 af = *reinterpret_cast<const bf16x8*>(&ab[m][kb]);
    #pragma unroll
    for (int ni = 0; ni < 2; ++ni){
      bf16x8 bfv = *reinterpret_cast<const bf16x8*>(woutT + (size_t)(C0 + ni*16 + m)*F_ + kb);
      acc2[ni] = mfma16(af, bfv, acc2[ni]);
    }
  }
  __syncthreads();
  // epilogue: x_new = x_old + v + b_out  (in-place x safe: own rows only)
  #pragma unroll
  for (int ni = 0; ni < 2; ++ni)
    #pragma unroll
    for (int rr = 0; rr < 4; ++rr){
      int row = q*4 + rr, col = C0 + ni*16 + m;
      size_t xo = (size_t)(b*N_ + R0 + row)*F_ + col;
      float xi = first ? emb[(size_t)zsh[row]*F_ + col] : x[xo];
      float nv = xi + acc2[ni][rr] + b_out[col];
      if (mode == 0) x[xo] = nv;
      ab[row][col & 127] = f2b(nv);
    }
  __syncthreads();

  // GEMM3: x_new @ (wi2t | waw1T)
  const u16* w3 = (mode == 0) ? wi2t : waw1T;
  f32x4 acc3[2];
  acc3[0] = (f32x4){0.f,0.f,0.f,0.f}; acc3[1] = (f32x4){0.f,0.f,0.f,0.f};
  #pragma unroll
  for (int ks = 0; ks < 4; ++ks){
    int kb = ks*32 + q*8;
    bf16x8 af = *reinterpret_cast<const bf16x8*>(&ab[m][kb]);
    #pragma unroll
    for (int ni = 0; ni < 2; ++ni){
      bf16x8 bfv = *reinterpret_cast<const bf16x8*>(w3 + (size_t)(C0 + ni*16 + m)*F_ + kb);
      acc3[ni] = mfma16(af, bfv, acc3[ni]);
    }
  }
  if (mode == 0){
    #pragma unroll
    for (int ni = 0; ni < 2; ++ni)
      #pragma unroll
      for (int rr = 0; rr < 4; ++rr)
        fb[(size_t)(b*N_ + R0 + q*4 + rr)*F_ + C0 + ni*16 + m] = f2b(acc3[ni][rr]);
  } else {
    #pragma unroll
    for (int ni = 0; ni < 2; ++ni)
      #pragma unroll
      for (int rr = 0; rr < 4; ++rr){
        int col = C0 + ni*16 + m;
        cs[q*4 + rr][col] = sspf(acc3[ni][rr] + b_aw1[col]) * w_aw2[col];
      }
    __syncthreads();
    if (tid < 128){
      int row = tid >> 3, seg = tid & 7;
      float s = 0.f;
      #pragma unroll
      for (int t = 0; t < 16; ++t) s += cs[row][seg*16 + t];
      psum[row][seg] = s;
    }
    __syncthreads();
    if (tid < 16){
      float s = 0.f;
      #pragma unroll
      for (int t = 0; t < 8; ++t) s += psum[tid][t];
      outp[b*N_ + R0 + tid] = s + b_aw2[0];
    }
  }
}

extern "C" void kernel_launch(void* const* d_in, const int* in_sizes, int n_in,
                              void* d_out, int out_size, void* d_ws, size_t ws_size,
                              hipStream_t stream){
  const int*   z       = (const int*)d_in[0];
  const float* r       = (const float*)d_in[1];
  const float* emb     = (const float*)d_in[2];
  const float* w_in2f  = (const float*)d_in[3];
  const float* w_f1    = (const float*)d_in[4];
  const float* b_f1    = (const float*)d_in[5];
  const float* w_f2    = (const float*)d_in[6];
  const float* b_f2    = (const float*)d_in[7];
  const float* w_f2out = (const float*)d_in[8];
  const float* b_f2out = (const float*)d_in[9];
  const float* w_out   = (const float*)d_in[10];
  const float* b_out   = (const float*)d_in[11];
  const float* w_aw1   = (const float*)d_in[12];
  const float* b_aw1   = (const float*)d_in[13];
  const float* w_aw2   = (const float*)d_in[14];
  const float* b_aw2   = (const float*)d_in[15];

  // workspace layout (6.33 MB)
  char* ws = (char*)d_ws;
  float* x     = (float*)(ws);                       // 2,097,152
  float* y     = (float*)(ws + 2097152);             // 2,097,152
  u16*   fbuf  = (u16*)(ws + 4194304);               // 1,048,576
  u16*   tab   = (u16*)(ws + 5242880);               // 1,048,576
  u16*   w1t   = (u16*)(ws + 6291456);               //    81,920
  u16*   w2t   = (u16*)(ws + 6373376);               //    32,768
  u16*   wi2t  = (u16*)(ws + 6406144);               //    32,768
  u16*   w2oT  = (u16*)(ws + 6438912);               //    32,768
  u16*   woT   = (u16*)(ws + 6471680);               //    32,768
  u16*   waw1T = (u16*)(ws + 6504448);               //    32,768

  k_setup<<<480, 256, 0, stream>>>(w_f1, w_f2, w_in2f, w_f2out, w_out, w_aw1,
                                   w1t, w2t, wi2t, w2oT, woT, waw1T);
  k_gentab<<<256, 256, 0, stream>>>(w1t, w2t, b_f1, b_f2, tab);
  k_lin<<<128, 256, 0, stream>>>(z, emb, wi2t, fbuf);
  // iter 1
  k_conv<<<1024, 256, 0, stream>>>(fbuf, tab, r, y);
  k_mlp<<<256, 256, 0, stream>>>(y, x, z, emb, w2oT, b_f2out, woT, b_out,
                                 wi2t, waw1T, b_aw1, w_aw2, b_aw2,
                                 fbuf, (float*)d_out, 1, 0);
  // iter 2
  k_conv<<<1024, 256, 0, stream>>>(fbuf, tab, r, y);
  k_mlp<<<256, 256, 0, stream>>>(y, x, z, emb, w2oT, b_f2out, woT, b_out,
                                 wi2t, waw1T, b_aw1, w_aw2, b_aw2,
                                 fbuf, (float*)d_out, 0, 0);
  // iter 3 (readout fused)
  k_conv<<<1024, 256, 0, stream>>>(fbuf, tab, r, y);
  k_mlp<<<256, 256, 0, stream>>>(y, x, z, emb, w2oT, b_f2out, woT, b_out,
                                 wi2t, waw1T, b_aw1, w_aw2, b_aw2,
                                 fbuf, (float*)d_out, 0, 1);
}